// Round 5
// baseline (169.243 us; speedup 1.0000x reference)
//
#include <hip/hip_runtime.h>
#include <hip/hip_bf16.h>

typedef __bf16 bf16;
typedef __bf16 bf16x8 __attribute__((ext_vector_type(8)));
typedef __bf16 bf16x4 __attribute__((ext_vector_type(4)));
typedef float  f32x4  __attribute__((ext_vector_type(4)));

#define LOG2E 1.44269504088896340736f

// B=2, S=2048, C=1024, H=16, D=64, M=B*S=4096
// qkv ws layout: Q [2][16][2048][64] | K [2][16][2048][64] | V^T [2][16][64][2048]

__device__ __forceinline__ void gl_lds16(const void* g, void* l) {
  __builtin_amdgcn_global_load_lds((__attribute__((address_space(1))) void*)g,
                                   (__attribute__((address_space(3))) void*)l,
                                   16, 0, 0);
}

__device__ __forceinline__ unsigned cvt_pk(float lo, float hi) {
  unsigned r;
  asm("v_cvt_pk_bf16_f32 %0, %1, %2" : "=v"(r) : "v"(lo), "v"(hi));
  return r;
}

__device__ __forceinline__ bf16x8 bits8(const unsigned* w) {
  union { unsigned u[4]; bf16x8 v; } u;
  u.u[0] = w[0]; u.u[1] = w[1]; u.u[2] = w[2]; u.u[3] = w[3];
  return u.v;
}

// ---------------------------------------------------------------------------
__global__ void cvt3_kernel(const float* __restrict__ x,
                            const float* __restrict__ w1,
                            const float* __restrict__ w2,
                            bf16* __restrict__ xb,
                            bf16* __restrict__ w1b,
                            bf16* __restrict__ w2b) {
  const int NX = 1048576, NW1 = 786432, NW2 = 262144; // float4 quads
  const int total = NX + NW1 + NW2;
  int i = blockIdx.x * blockDim.x + threadIdx.x;
  const int stride = gridDim.x * blockDim.x;
  for (; i < total; i += stride) {
    const float* s; bf16* d; int j;
    if (i < NX)            { s = x;  d = xb;  j = i; }
    else if (i < NX + NW1) { s = w1; d = w1b; j = i - NX; }
    else                   { s = w2; d = w2b; j = i - NX - NW1; }
    f32x4 v = ((const f32x4*)s)[j];
    bf16x4 o;
    o[0] = (bf16)v[0]; o[1] = (bf16)v[1]; o[2] = (bf16)v[2]; o[3] = (bf16)v[3];
    ((bf16x4*)d)[j] = o;
  }
}

// ---------------------------------------------------------------------------
// GEMM: C[m][n] = sum_k A[m][k]*Bw[n][k] + bias[n]; 128x128 tile, BK=64, 4 waves.
// EPI 0: scatter to qkv ws (Q pre-scaled by 0.125*LOG2E, V transposed per head).
// EPI 1: fp32 out [M][N].
// ---------------------------------------------------------------------------
template<int EPI>
__global__ __launch_bounds__(256) void gemm_bt(const bf16* __restrict__ A,
                                               const bf16* __restrict__ Bw,
                                               const float* __restrict__ bias,
                                               void* __restrict__ outp,
                                               int M, int N, int K) {
  __shared__ bf16 As[128 * 64];
  __shared__ bf16 Bs[128 * 64];
  const int tid  = threadIdx.x;
  const int lane = tid & 63;
  const int w    = tid >> 6;
  const int wm   = w >> 1, wn = w & 1;
  const int mBase = blockIdx.y * 128;
  const int nBase = blockIdx.x * 128;
  const int rl = lane & 15;
  const int qg = lane >> 4;
  const int srow = tid >> 3;
  const int schunk = tid & 7;

  f32x4 acc[4][4] = {};

  for (int k0 = 0; k0 < K; k0 += 64) {
    __syncthreads();
#pragma unroll
    for (int rr = 0; rr < 4; ++rr) {
      int r  = rr * 32 + srow;
      int cs = schunk ^ (r & 7);
      gl_lds16(A  + (size_t)(mBase + r) * K + k0 + cs * 8, As + r * 64 + schunk * 8);
      gl_lds16(Bw + (size_t)(nBase + r) * K + k0 + cs * 8, Bs + r * 64 + schunk * 8);
    }
    __syncthreads();
#pragma unroll
    for (int ks = 0; ks < 2; ++ks) {
      bf16x8 af[4], bfr[4];
      const int cl = ks * 4 + qg;
#pragma unroll
      for (int mf = 0; mf < 4; ++mf) {
        int r = wm * 64 + mf * 16 + rl;
        af[mf] = *(const bf16x8*)(As + r * 64 + (cl ^ (r & 7)) * 8);
      }
#pragma unroll
      for (int nf = 0; nf < 4; ++nf) {
        int r = wn * 64 + nf * 16 + rl;
        bfr[nf] = *(const bf16x8*)(Bs + r * 64 + (cl ^ (r & 7)) * 8);
      }
#pragma unroll
      for (int mf = 0; mf < 4; ++mf)
#pragma unroll
        for (int nf = 0; nf < 4; ++nf)
          acc[mf][nf] = __builtin_amdgcn_mfma_f32_16x16x32_bf16(af[mf], bfr[nf],
                                                                acc[mf][nf], 0, 0, 0);
    }
  }

#pragma unroll
  for (int mf = 0; mf < 4; ++mf) {
#pragma unroll
    for (int nf = 0; nf < 4; ++nf) {
      int n = nBase + wn * 64 + nf * 16 + rl;
      float bv = bias[n];
#pragma unroll
      for (int j = 0; j < 4; ++j) {
        int m = mBase + wm * 64 + mf * 16 + qg * 4 + j;
        float val = acc[mf][nf][j] + bv;
        if (EPI == 0) {
          int t = n >> 10, rem = n & 1023;
          int h = rem >> 6, d = rem & 63;
          int b = m >> 11, s = m & 2047;
          bf16* q = (bf16*)outp;
          size_t hb = (size_t)(b * 16 + h);
          if (t == 0) {
            q[(hb * 2048 + s) * 64 + d] = (bf16)(val * (0.125f * LOG2E));
          } else if (t == 1) {
            q[4194304 + (hb * 2048 + s) * 64 + d] = (bf16)val;
          } else {
            q[8388608 + (hb * 64 + d) * 2048 + s] = (bf16)val;
          }
        } else {
          ((float*)outp)[(size_t)m * N + n] = val;
        }
      }
    }
  }
}

// ---------------------------------------------------------------------------
// Flash attention with ALiBi. 4 waves x 16 q-rows, KT=64.
// Proven round-3 sync: barrier -> STAGE -> barrier -> compute (single buffer).
// Swapped QK^T -> lane-local softmax -> butterfly-packed P -> x32 PV MFMA.
// ALiBi pruning: skip far-future tiles; 1-add bias for fully-clamped past.
// ---------------------------------------------------------------------------
__global__ __launch_bounds__(256) void attn_kernel(const bf16* __restrict__ qkv,
                                                   bf16* __restrict__ attout) {
  __shared__ bf16 Ks[64 * 64];
  __shared__ bf16 Vt[64 * 64];
  __shared__ bf16 ONES[16 * 64];

  const int tid  = threadIdx.x;
  const int lane = tid & 63;
  const int w    = tid >> 6;
  // XCD swizzle: xcd gets head pair {x, 15-x} (balances pruning skew).
  const int id  = blockIdx.x;
  const int xcd = id & 7;
  const int sel = (id >> 3) & 1;
  const int b   = (id >> 4) & 1;
  const int qt  = id >> 5;
  const int h   = sel ? (15 - xcd) : xcd;
  const int bh  = b * 16 + h;
  const size_t headoff = (size_t)bh * 131072;
  const bf16* Qg = qkv + headoff;
  const bf16* Kg = qkv + 4194304 + headoff;
  const bf16* Vg = qkv + 8388608 + headoff;   // [64][2048]

  const int rl = lane & 15;
  const int qg = lane >> 4;
  const int srow = tid >> 3;
  const int schunk = tid & 7;
  const int cs8 = (schunk ^ (srow & 7)) * 8;

  ((bf16x4*)ONES)[tid] = bf16x4{(bf16)1.f, (bf16)1.f, (bf16)1.f, (bf16)1.f};

  // Q fragments (pre-scaled by 0.125*LOG2E)
  const int qrow = qt * 64 + w * 16 + rl;
  bf16x8 qf[2];
  qf[0] = *(const bf16x8*)(Qg + (size_t)qrow * 64 + qg * 8);
  qf[1] = *(const bf16x8*)(Qg + (size_t)qrow * 64 + 32 + qg * 8);

  // hoisted LDS offsets
  int koff[4][2], ooff[2];
#pragma unroll
  for (int cf = 0; cf < 4; ++cf) {
    int r = cf * 16 + rl, r7 = r & 7;
#pragma unroll
    for (int ks = 0; ks < 2; ++ks)
      koff[cf][ks] = r * 64 + (((ks * 4 + qg) ^ r7) << 3);
  }
#pragma unroll
  for (int ks = 0; ks < 2; ++ks)
    ooff[ks] = rl * 64 + (((ks * 4 + qg) ^ (rl & 7)) << 3);

  // hoisted stage pointers (proven round-3 form)
  const bf16* ksrc = Kg + (size_t)srow * 64 + cs8;
  const bf16* vsrc = Vg + (size_t)srow * 2048 + cs8;
  bf16* kdst = Ks + srow * 64 + schunk * 8;
  bf16* vdst = Vt + srow * 64 + schunk * 8;

  // softmax state (base-2, running max folded into basep/Mm)
  const float slope2 = exp2f(-0.5f * (float)(h + 1)) * LOG2E;
  const float nslope = -slope2;
  const float kstep  = slope2 * 64.0f;
  float basep = slope2 * (float)(qrow - qg * 4);
  float Mm    = 8.0f * LOG2E;

  // tile pruning bounds (block-uniform)
  const float q0f = (float)(qt * 64);
  int ktEnd = (int)floorf((q0f + 63.f + 40.f / slope2) * (1.f / 64.f)) + 1;
  if (ktEnd > 32) ktEnd = 32;
  int ktClamp = (int)floorf((q0f - 63.f - 11.6f / slope2) * (1.f / 64.f)) + 1;
  if (ktClamp < 0) ktClamp = 0;

  f32x4 o[5] = {};                  // o[4] = lsum (ones block)

  for (int kt = 0; kt < ktEnd; ++kt) {
    __syncthreads();                // all reads of prev tile complete
    gl_lds16(ksrc,             kdst);
    gl_lds16(ksrc + 32 * 64,   kdst + 32 * 64);
    gl_lds16(vsrc,             vdst);
    gl_lds16(vsrc + 32 * 2048, vdst + 32 * 64);
    ksrc += 64 * 64; vsrc += 64;
    __syncthreads();                // stage drained (vmcnt0+barrier)

    // swapped QK^T: pe[cf][j] = score(q=qrow, k = 64kt + 16cf + 4qg + j)
    f32x4 sc[4] = {};
    __builtin_amdgcn_s_setprio(1);
#pragma unroll
    for (int cf = 0; cf < 4; ++cf)
#pragma unroll
      for (int ks = 0; ks < 2; ++ks) {
        bf16x8 kf = *(const bf16x8*)(Ks + koff[cf][ks]);
        sc[cf] = __builtin_amdgcn_mfma_f32_16x16x32_bf16(kf, qf[ks], sc[cf], 0, 0, 0);
      }
    __builtin_amdgcn_s_setprio(0);

    // bias + row max
    float pe[4][4];
    if (kt >= ktClamp) {
#pragma unroll
      for (int cf = 0; cf < 4; ++cf)
#pragma unroll
        for (int j = 0; j < 4; ++j)
          pe[cf][j] = sc[cf][j] +
              fminf(__builtin_fmaf(nslope, (float)(cf * 16 + j), basep), Mm);
    } else {
#pragma unroll
      for (int cf = 0; cf < 4; ++cf)
#pragma unroll
        for (int j = 0; j < 4; ++j)
          pe[cf][j] = sc[cf][j] + Mm;   // fully clamped: bias == 8
    }
    float mxa = fmaxf(fmaxf(pe[0][0], pe[0][1]), fmaxf(pe[0][2], pe[0][3]));
    float mxb = fmaxf(fmaxf(pe[1][0], pe[1][1]), fmaxf(pe[1][2], pe[1][3]));
    float mxc = fmaxf(fmaxf(pe[2][0], pe[2][1]), fmaxf(pe[2][2], pe[2][3]));
    float mxd = fmaxf(fmaxf(pe[3][0], pe[3][1]), fmaxf(pe[3][2], pe[3][3]));
    float mx = fmaxf(fmaxf(mxa, mxb), fmaxf(mxc, mxd));
    mx = fmaxf(mx, __shfl_xor(mx, 16));
    mx = fmaxf(mx, __shfl_xor(mx, 32));

    if (__any(mx > 8.0f)) {          // defer-max (THR=8, base-2)
      float d = fmaxf(mx, 0.0f);
      basep -= d; Mm -= d;
      float alpha = exp2f(-d);
      float av[4];
#pragma unroll
      for (int j = 0; j < 4; ++j)
        av[j] = __shfl(alpha, qg * 4 + j);
#pragma unroll
      for (int dg = 0; dg < 5; ++dg)
#pragma unroll
        for (int j = 0; j < 4; ++j)
          o[dg][j] *= av[j];
#pragma unroll
      for (int cf = 0; cf < 4; ++cf)
#pragma unroll
        for (int j = 0; j < 4; ++j)
          pe[cf][j] = exp2f(pe[cf][j] - d);
    } else {
#pragma unroll
      for (int cf = 0; cf < 4; ++cf)
#pragma unroll
        for (int j = 0; j < 4; ++j)
          pe[cf][j] = exp2f(pe[cf][j]);
    }

    // pack P (cvt_pk) + butterfly exchange -> x32 A-fragments
    unsigned Wd[4][2];
#pragma unroll
    for (int cf = 0; cf < 4; ++cf) {
      Wd[cf][0] = cvt_pk(pe[cf][0], pe[cf][1]);
      Wd[cf][1] = cvt_pk(pe[cf][2], pe[cf][3]);
    }
    const bool hi32  = (lane & 32) != 0;
    const bool odd16 = (lane & 16) != 0;
    unsigned Aown[2], Aoth[2], Bown[2], Both[2];
#pragma unroll
    for (int u = 0; u < 2; ++u) {
      Aown[u] = hi32 ? Wd[1][u] : Wd[0][u];
      Aoth[u] = (unsigned)__shfl_xor((int)(hi32 ? Wd[0][u] : Wd[1][u]), 32);
      Bown[u] = hi32 ? Wd[3][u] : Wd[2][u];
      Both[u] = (unsigned)__shfl_xor((int)(hi32 ? Wd[2][u] : Wd[3][u]), 32);
    }
    const bool sendOwn = odd16 ^ hi32;
    unsigned fa[4], fb[4];
#pragma unroll
    for (int u = 0; u < 2; ++u) {
      unsigned rA = (unsigned)__shfl_xor((int)(sendOwn ? Aown[u] : Aoth[u]), 16);
      unsigned rB = (unsigned)__shfl_xor((int)(sendOwn ? Bown[u] : Both[u]), 16);
      fa[u]     = odd16 ? rA : (hi32 ? Aoth[u] : Aown[u]);
      fa[2 + u] = odd16 ? (hi32 ? Aown[u] : Aoth[u]) : rA;
      fb[u]     = odd16 ? rB : (hi32 ? Both[u] : Bown[u]);
      fb[2 + u] = odd16 ? (hi32 ? Bown[u] : Both[u]) : rB;
    }
    bf16x8 pa0 = bits8(fa), pa1 = bits8(fb);

    // PV: O[q][d] += P[q][k] V[k][d] (x32 MFMA, conflict-free b128 V reads)
    __builtin_amdgcn_s_setprio(1);
#pragma unroll
    for (int dg = 0; dg < 4; ++dg) {
      bf16x8 vb = *(const bf16x8*)(Vt + koff[dg][0]);
      o[dg] = __builtin_amdgcn_mfma_f32_16x16x32_bf16(pa0, vb, o[dg], 0, 0, 0);
    }
    {
      bf16x8 vb = *(const bf16x8*)(ONES + ooff[0]);
      o[4] = __builtin_amdgcn_mfma_f32_16x16x32_bf16(pa0, vb, o[4], 0, 0, 0);
    }
#pragma unroll
    for (int dg = 0; dg < 4; ++dg) {
      bf16x8 vb = *(const bf16x8*)(Vt + koff[dg][1]);
      o[dg] = __builtin_amdgcn_mfma_f32_16x16x32_bf16(pa1, vb, o[dg], 0, 0, 0);
    }
    {
      bf16x8 vb = *(const bf16x8*)(ONES + ooff[1]);
      o[4] = __builtin_amdgcn_mfma_f32_16x16x32_bf16(pa1, vb, o[4], 0, 0, 0);
    }
    __builtin_amdgcn_s_setprio(0);

    basep -= kstep;
  }

  // epilogue: PV D layout row = qg*4+j, col = rl
  float inv[4];
#pragma unroll
  for (int j = 0; j < 4; ++j)
    inv[j] = 1.0f / o[4][j];

#pragma unroll
  for (int dg = 0; dg < 4; ++dg)
#pragma unroll
    for (int j = 0; j < 4; ++j) {
      int row = qt * 64 + w * 16 + qg * 4 + j;
      int col = h * 64 + dg * 16 + rl;
      attout[((size_t)b * 2048 + row) * 1024 + col] = (bf16)(o[dg][j] * inv[j]);
    }
}

// ---------------------------------------------------------------------------
extern "C" void kernel_launch(void* const* d_in, const int* in_sizes, int n_in,
                              void* d_out, int out_size, void* d_ws, size_t ws_size,
                              hipStream_t stream) {
  const float* x  = (const float*)d_in[0];
  const float* w1 = (const float*)d_in[1];
  const float* b1 = (const float*)d_in[2];
  const float* w2 = (const float*)d_in[3];
  const float* b2 = (const float*)d_in[4];
  float* out = (float*)d_out;

  char* ws = (char*)d_ws;
  bf16* xb    = (bf16*)(ws);
  bf16* w1b   = (bf16*)(ws + 8388608);
  bf16* w2b   = (bf16*)(ws + 14680064);
  bf16* qkvb  = (bf16*)(ws + 16777216);   // Q | K | V^T sections
  bf16* attnb = (bf16*)(ws + 41943040);

  cvt3_kernel<<<2048, 256, 0, stream>>>(x, w1, w2, xb, w1b, w2b);
  gemm_bt<0><<<dim3(24, 32), 256, 0, stream>>>(xb, w1b, b1, (void*)qkvb, 4096, 3072, 1024);
  attn_kernel<<<1024, 256, 0, stream>>>(qkvb, attnb);
  gemm_bt<1><<<dim3(8, 32), 256, 0, stream>>>(attnb, w2b, b2, (void*)out, 4096, 1024, 1024);
}